// Round 4
// baseline (273.288 us; speedup 1.0000x reference)
//
#include <hip/hip_runtime.h>
#include <hip/hip_bf16.h>
#include <stdint.h>
#include <string.h>

#define NV 40962     // vertices
#define NC 64        // in channels
#define NO 64        // out channels
#define NM 27        // neighbors*3
#define NB 4         // batch
#define KP 576       // K = 9*64, permuted t = k*64 + c (k-major)
#define NPAD 28      // padded pairs per vertex (112 B rows, 16B-aligned)

using frag16 = __attribute__((ext_vector_type(8))) short;  // 8 bf16
using f32x4  = __attribute__((ext_vector_type(4))) float;  // MFMA acc
using v2f    = __attribute__((ext_vector_type(2))) float;  // packed fma

__device__ inline float bfbits(unsigned int hi16) {
    union { unsigned int i; float f; } c; c.i = hi16; return c.f;
}
__device__ inline unsigned int pack_bf2(float a, float b) {
    float2 f2 = make_float2(a, b);
    __hip_bfloat162 h = __float22bfloat162_rn(f2);
    unsigned int u; memcpy(&u, &h, 4); return u;
}
__device__ inline unsigned short f2bf16(float f) {
    union { float f; unsigned int i; } c; c.f = f;
    unsigned int x = c.i;
    return (unsigned short)((x + 0x7FFFu + ((x >> 16) & 1u)) >> 16);  // RNE
}
__device__ inline unsigned int comp(const uint4& v, int i) {
    switch (i & 3) { case 0: return v.x; case 1: return v.y; case 2: return v.z; default: return v.w; }
}

// ---- prep: W -> Wp bf16 (t = k*64+c), and (idx,w) -> packed pairs ----
__global__ __launch_bounds__(256) void prep_kernel(const float* __restrict__ W,
                                                   const int* __restrict__ nidx,
                                                   const float* __restrict__ nwt,
                                                   unsigned short* __restrict__ Wp,
                                                   unsigned int* __restrict__ pairs) {
    int i = blockIdx.x * 256 + threadIdx.x;
    if (i < NO * KP) {
        int o = i / KP, t = i % KP;
        int k = t >> 6, c = t & 63;
        Wp[i] = f2bf16(W[o * 576 + c * 9 + k]);
    }
    if (i < NV * NPAD) {
        int v = i / NPAD, j = i - v * NPAD;
        unsigned int pv = 0;
        if (j < NM) {
            unsigned int id = (unsigned int)nidx[v * NM + j];   // < 40962, fits 16 bits
            unsigned int wb = (unsigned int)f2bf16(nwt[v * NM + j]);
            pv = (wb << 16) | (id & 0xffffu);
        }
        pairs[i] = pv;
    }
}

// ---- x (B,C,V) fp32 -> xt (B,V,C) bf16 ----
__global__ __launch_bounds__(256) void transpose_kernel(const float* __restrict__ x,
                                                        unsigned short* __restrict__ xt) {
    __shared__ float tile[64][65];
    int b = blockIdx.y;
    int v0 = blockIdx.x * 64;
    int t = threadIdx.x;
    int tv = t & 63, tc = t >> 6;
    const float* xb = x + (size_t)b * NC * NV;
    #pragma unroll
    for (int i = 0; i < 16; i++) {
        int c = tc + i * 4;
        int v = v0 + tv;
        tile[c][tv] = (v < NV) ? xb[(size_t)c * NV + v] : 0.f;
    }
    __syncthreads();
    unsigned short* xtb = xt + (size_t)b * NV * NC;
    #pragma unroll
    for (int i = 0; i < 2; i++) {
        int r = i * 32 + (t >> 3);
        int ch0 = (t & 7) * 8;
        int v = v0 + r;
        if (v < NV) {
            unsigned int o[4];
            #pragma unroll
            for (int j = 0; j < 4; j++)
                o[j] = pack_bf2(tile[ch0 + 2 * j][r], tile[ch0 + 2 * j + 1][r]);
            *(uint4*)(xtb + (size_t)v * NC + ch0) = *(const uint4*)o;
        }
    }
}

// ---- fused gather + MFMA GEMM, ZERO LDS ----
// block = 64 = 1 wave; wave computes 16 vertices x 64 outputs.
// lane = (q = lane>>4, m = lane&15): lane owns vertex n0+m, channels
// q*8..q*8+7 and 32+q*8..32+q*8+7 -> exactly the 16x16x32 A-frag layout
// A[m=lane&15][k=q*8+j] for all 18 k-steps. No LDS transform needed.
__global__ __launch_bounds__(64, 2) void fused_kernel(
    const unsigned short* __restrict__ xt,
    const unsigned int* __restrict__ pairs,
    const unsigned short* __restrict__ Wp,
    const float* __restrict__ bias,
    float* __restrict__ out)
{
    int lane = threadIdx.x;
    int q = lane >> 4;          // 0..3: channel quad
    int m = lane & 15;          // vertex within tile
    int b = blockIdx.y;
    int n0 = blockIdx.x * 16;
    int vtx = n0 + m; if (vtx >= NV) vtx = NV - 1;
    const char* xb = (const char*)(xt + (size_t)b * NV * NC);
    int cofs = q * 16;          // byte offset of lower 8-channel group

    // all 27 (idx,w) pairs for this lane's vertex (7 dwordx4, issued together)
    uint4 pr[7];
    {
        const uint4* pp = (const uint4*)(pairs + (size_t)vtx * NPAD);
        #pragma unroll
        for (int j = 0; j < 7; j++) pr[j] = pp[j];
    }

    // fp32 accumulators: 9 k-slots x 16 channels (as v2f pairs) = 144 VGPRs
    v2f acc[9][8];
    #pragma unroll
    for (int k = 0; k < 9; k++)
        #pragma unroll
        for (int d = 0; d < 8; d++) acc[k][d] = (v2f){0.f, 0.f};

    // gather sweep: 54 independent dwordx4 loads, 2-deep software pipeline
    uint4 ua[2], ub[2];
    {
        unsigned int pm = comp(pr[0], 0);
        const char* base = xb + ((pm & 0xffffu) << 7) + cofs;
        ua[0] = *(const uint4*)base;
        ub[0] = *(const uint4*)(base + 64);
    }
    #pragma unroll
    for (int mm = 0; mm < NM; mm++) {
        if (mm + 1 < NM) {
            unsigned int pn = comp(pr[(mm + 1) >> 2], mm + 1);
            const char* base = xb + ((pn & 0xffffu) << 7) + cofs;
            ua[(mm + 1) & 1] = *(const uint4*)base;
            ub[(mm + 1) & 1] = *(const uint4*)(base + 64);
        }
        unsigned int pm = comp(pr[mm >> 2], mm);
        float wv = bfbits(pm & 0xffff0000u);
        v2f w2 = {wv, wv};
        int k = mm / 3;  // compile-time after unroll
        uint4 u0 = ua[mm & 1], u1 = ub[mm & 1];
        const unsigned int d0[4] = {u0.x, u0.y, u0.z, u0.w};
        const unsigned int d1[4] = {u1.x, u1.y, u1.z, u1.w};
        #pragma unroll
        for (int d = 0; d < 4; d++) {
            v2f x0 = {bfbits(d0[d] << 16), bfbits(d0[d] & 0xffff0000u)};
            v2f x1 = {bfbits(d1[d] << 16), bfbits(d1[d] & 0xffff0000u)};
            acc[k][d]     = __builtin_elementwise_fma(x0, w2, acc[k][d]);
            acc[k][4 + d] = __builtin_elementwise_fma(x1, w2, acc[k][4 + d]);
        }
    }

    // pack to bf16 A-fragment dwords: pk[kslot][0..3] = channels q*8+0..7,
    // pk[kslot][4..7] = channels 32+q*8+0..7
    unsigned int pk[9][8];
    #pragma unroll
    for (int k = 0; k < 9; k++)
        #pragma unroll
        for (int d = 0; d < 8; d++)
            pk[k][d] = pack_bf2(acc[k][d][0], acc[k][d][1]);

    // GEMM: 18 k-steps, A from registers, B from Wp (L2-hot)
    const unsigned short* wrow = Wp + q * 8;
    f32x4 c0 = {0.f, 0.f, 0.f, 0.f};
    f32x4 c1 = {0.f, 0.f, 0.f, 0.f};
    f32x4 c2 = {0.f, 0.f, 0.f, 0.f};
    f32x4 c3 = {0.f, 0.f, 0.f, 0.f};
    #pragma unroll
    for (int kk = 0; kk < 18; kk++) {
        unsigned int af[4];
        #pragma unroll
        for (int d = 0; d < 4; d++) af[d] = pk[kk >> 1][(kk & 1) * 4 + d];
        frag16 a; memcpy(&a, af, 16);
        frag16 b0 = *(const frag16*)(wrow + (size_t)(0 * 16 + m) * KP + kk * 32);
        frag16 b1 = *(const frag16*)(wrow + (size_t)(1 * 16 + m) * KP + kk * 32);
        frag16 b2 = *(const frag16*)(wrow + (size_t)(2 * 16 + m) * KP + kk * 32);
        frag16 b3 = *(const frag16*)(wrow + (size_t)(3 * 16 + m) * KP + kk * 32);
        c0 = __builtin_amdgcn_mfma_f32_16x16x32_bf16(a, b0, c0, 0, 0, 0);
        c1 = __builtin_amdgcn_mfma_f32_16x16x32_bf16(a, b1, c1, 0, 0, 0);
        c2 = __builtin_amdgcn_mfma_f32_16x16x32_bf16(a, b2, c2, 0, 0, 0);
        c3 = __builtin_amdgcn_mfma_f32_16x16x32_bf16(a, b3, c3, 0, 0, 0);
    }

    // epilogue: D[row = q*4+i (vertex)][col = m+16j (output)], + bias
    size_t outb = (size_t)b * NO * NV;
    f32x4 cc[4] = {c0, c1, c2, c3};
    #pragma unroll
    for (int j = 0; j < 4; j++) {
        int o = j * 16 + m;
        float bo = bias[o];
        #pragma unroll
        for (int i = 0; i < 4; i++) {
            int n = n0 + q * 4 + i;
            if (n < NV) out[outb + (size_t)o * NV + n] = cc[j][i] + bo;
        }
    }
}

extern "C" void kernel_launch(void* const* d_in, const int* in_sizes, int n_in,
                              void* d_out, int out_size, void* d_ws, size_t ws_size,
                              hipStream_t stream) {
    const float* x    = (const float*)d_in[0];  // (4,64,40962) fp32
    const int*   nidx = (const int*)d_in[1];    // (40962,27) int32
    const float* nwt  = (const float*)d_in[2];  // (40962,27) fp32
    const float* W    = (const float*)d_in[3];  // (64,576) fp32
    const float* bias = (const float*)d_in[4];  // (64,) fp32
    float* out = (float*)d_out;                 // (4,64,40962) fp32

    unsigned short* Wp    = (unsigned short*)d_ws;                       // 72 KB
    unsigned short* xt    = (unsigned short*)((char*)d_ws + 131072);     // 21 MB
    unsigned int*   pairs = (unsigned int*)((char*)d_ws + 131072 + (size_t)NB * NV * NC * 2);  // 4.6 MB

    prep_kernel<<<dim3((NV * NPAD + 255) / 256), 256, 0, stream>>>(W, nidx, nwt, Wp, pairs);
    transpose_kernel<<<dim3((NV + 63) / 64, NB), 256, 0, stream>>>(x, xt);
    fused_kernel<<<dim3((NV + 15) / 16, NB), 64, 0, stream>>>(xt, pairs, Wp, bias, out);
}

// Round 5
// 230.613 us; speedup vs baseline: 1.1850x; 1.1850x over previous
//
#include <hip/hip_runtime.h>
#include <hip/hip_bf16.h>
#include <stdint.h>
#include <string.h>

#define NV 40962     // vertices
#define NC 64        // in channels
#define NO 64        // out channels
#define NM 27        // neighbors*3
#define NB 4         // batch
#define KP 576       // K = 9*64, permuted t = k*64 + c (k-major)
#define NPAD 28      // padded pairs per vertex (112 B rows, 16B-aligned)

using frag16 = __attribute__((ext_vector_type(8))) short;  // 8 bf16
using f32x4  = __attribute__((ext_vector_type(4))) float;  // MFMA acc
using v2f    = __attribute__((ext_vector_type(2))) float;  // packed fma

__device__ inline float bfbits(unsigned int hi16) {
    union { unsigned int i; float f; } c; c.i = hi16; return c.f;
}
__device__ inline unsigned int pack_bf2(float a, float b) {
    float2 f2 = make_float2(a, b);
    __hip_bfloat162 h = __float22bfloat162_rn(f2);
    unsigned int u; memcpy(&u, &h, 4); return u;
}
__device__ inline unsigned short f2bf16(float f) {
    union { float f; unsigned int i; } c; c.f = f;
    unsigned int x = c.i;
    return (unsigned short)((x + 0x7FFFu + ((x >> 16) & 1u)) >> 16);  // RNE
}
__device__ inline unsigned int comp(const uint4& v, int i) {
    switch (i & 3) { case 0: return v.x; case 1: return v.y; case 2: return v.z; default: return v.w; }
}

// ---- prep: W -> Wp bf16 (t = k*64+c), and (idx,w) -> packed pairs ----
__global__ __launch_bounds__(256) void prep_kernel(const float* __restrict__ W,
                                                   const int* __restrict__ nidx,
                                                   const float* __restrict__ nwt,
                                                   unsigned short* __restrict__ Wp,
                                                   unsigned int* __restrict__ pairs) {
    int i = blockIdx.x * 256 + threadIdx.x;
    if (i < NO * KP) {
        int o = i / KP, t = i % KP;
        int k = t >> 6, c = t & 63;
        Wp[i] = f2bf16(W[o * 576 + c * 9 + k]);
    }
    if (i < NV * NPAD) {
        int v = i / NPAD, j = i - v * NPAD;
        unsigned int pv = 0;
        if (j < NM) {
            unsigned int id = (unsigned int)nidx[v * NM + j];   // < 40962, fits 16 bits
            unsigned int wb = (unsigned int)f2bf16(nwt[v * NM + j]);
            pv = (wb << 16) | (id & 0xffffu);
        }
        pairs[i] = pv;
    }
}

// ---- x (B,C,V) fp32 -> xt (B,V,C) bf16 ----
__global__ __launch_bounds__(256) void transpose_kernel(const float* __restrict__ x,
                                                        unsigned short* __restrict__ xt) {
    __shared__ float tile[64][65];
    int b = blockIdx.y;
    int v0 = blockIdx.x * 64;
    int t = threadIdx.x;
    int tv = t & 63, tc = t >> 6;
    const float* xb = x + (size_t)b * NC * NV;
    #pragma unroll
    for (int i = 0; i < 16; i++) {
        int c = tc + i * 4;
        int v = v0 + tv;
        tile[c][tv] = (v < NV) ? xb[(size_t)c * NV + v] : 0.f;
    }
    __syncthreads();
    unsigned short* xtb = xt + (size_t)b * NV * NC;
    #pragma unroll
    for (int i = 0; i < 2; i++) {
        int r = i * 32 + (t >> 3);
        int ch0 = (t & 7) * 8;
        int v = v0 + r;
        if (v < NV) {
            unsigned int o[4];
            #pragma unroll
            for (int j = 0; j < 4; j++)
                o[j] = pack_bf2(tile[ch0 + 2 * j][r], tile[ch0 + 2 * j + 1][r]);
            *(uint4*)(xtb + (size_t)v * NC + ch0) = *(const uint4*)o;
        }
    }
}

// ---- fused gather + MFMA GEMM, zero LDS, per-kslot interleave ----
// block = 64 = 1 wave; wave = 16 vertices x 64 outputs x 2 BATCHES.
// lane = (q = lane>>4, m = lane&15). Lane's gathered channels q*8..+7 (lo)
// and 32+q*8..+7 (hi) ARE the A-frag layout for k-steps 2k / 2k+1.
// Per k-slot: 12 gathers (2 batches x 3 neighbors x 2 halves), 32 fp32 acc,
// 2x2 A-frags, 16 MFMAs. 1-slot gather lookahead; C stays in AGPRs.
__global__ __launch_bounds__(64, 2) void fused_kernel(
    const unsigned short* __restrict__ xt,
    const unsigned int* __restrict__ pairs,
    const unsigned short* __restrict__ Wp,
    const float* __restrict__ bias,
    float* __restrict__ out)
{
    int lane = threadIdx.x;
    int q = lane >> 4;          // channel quad
    int m = lane & 15;          // vertex within tile
    int bp = blockIdx.y;        // batch pair: batches 2bp, 2bp+1
    int n0 = blockIdx.x * 16;
    int vtx = n0 + m; if (vtx >= NV) vtx = NV - 1;
    const char* xb0 = (const char*)xt + (size_t)(2 * bp) * NV * NC * 2;
    const char* xb1 = xb0 + (size_t)NV * NC * 2;
    int cofs = q * 16;

    // all 27 (idx|bf16 w) pairs for this lane's vertex
    uint4 pr[7];
    {
        const uint4* pp = (const uint4*)(pairs + (size_t)vtx * NPAD);
        #pragma unroll
        for (int j = 0; j < 7; j++) pr[j] = pp[j];
    }

    f32x4 c[2][4];
    #pragma unroll
    for (int bb = 0; bb < 2; bb++)
        #pragma unroll
        for (int j = 0; j < 4; j++) c[bb][j] = (f32x4){0.f, 0.f, 0.f, 0.f};

    uint4 ga[2][2][3], gb[2][2][3];  // [buf][batch][neighbor]

    // prologue: issue k-slot 0 gathers
    #pragma unroll
    for (int j = 0; j < 3; j++) {
        unsigned int pm = comp(pr[0], j);
        unsigned int off = ((pm & 0xffffu) << 7) + cofs;
        ga[0][0][j] = *(const uint4*)(xb0 + off);
        gb[0][0][j] = *(const uint4*)(xb0 + off + 64);
        ga[0][1][j] = *(const uint4*)(xb1 + off);
        gb[0][1][j] = *(const uint4*)(xb1 + off + 64);
    }

    const unsigned short* wrow = Wp + q * 8;

    #pragma unroll
    for (int k = 0; k < 9; k++) {
        int cur = k & 1, nxt = cur ^ 1;
        // lookahead: issue k+1's 12 gathers before consuming k's
        if (k < 8) {
            #pragma unroll
            for (int j = 0; j < 3; j++) {
                int mm = 3 * (k + 1) + j;
                unsigned int pm = comp(pr[mm >> 2], mm);
                unsigned int off = ((pm & 0xffffu) << 7) + cofs;
                ga[nxt][0][j] = *(const uint4*)(xb0 + off);
                gb[nxt][0][j] = *(const uint4*)(xb0 + off + 64);
                ga[nxt][1][j] = *(const uint4*)(xb1 + off);
                gb[nxt][1][j] = *(const uint4*)(xb1 + off + 64);
            }
        }
        // accumulate k's 3 neighbors, 16 channels x 2 batches
        v2f accA[2][4], accB[2][4];
        #pragma unroll
        for (int bb = 0; bb < 2; bb++)
            #pragma unroll
            for (int d = 0; d < 4; d++) {
                accA[bb][d] = (v2f){0.f, 0.f};
                accB[bb][d] = (v2f){0.f, 0.f};
            }
        #pragma unroll
        for (int j = 0; j < 3; j++) {
            int mm = 3 * k + j;
            unsigned int pm = comp(pr[mm >> 2], mm);
            float wv = bfbits(pm & 0xffff0000u);
            v2f w2 = {wv, wv};
            #pragma unroll
            for (int bb = 0; bb < 2; bb++) {
                uint4 u0 = bb ? ga[cur][1][j] : ga[cur][0][j];
                uint4 u1 = bb ? gb[cur][1][j] : gb[cur][0][j];
                const unsigned int d0[4] = {u0.x, u0.y, u0.z, u0.w};
                const unsigned int d1[4] = {u1.x, u1.y, u1.z, u1.w};
                #pragma unroll
                for (int d = 0; d < 4; d++) {
                    v2f x0 = {bfbits(d0[d] << 16), bfbits(d0[d] & 0xffff0000u)};
                    v2f x1 = {bfbits(d1[d] << 16), bfbits(d1[d] & 0xffff0000u)};
                    accA[bb][d] = __builtin_elementwise_fma(x0, w2, accA[bb][d]);
                    accB[bb][d] = __builtin_elementwise_fma(x1, w2, accB[bb][d]);
                }
            }
        }
        // pack A-frags and run k-steps 2k (lo) and 2k+1 (hi)
        frag16 a0[2], a1[2];
        #pragma unroll
        for (int bb = 0; bb < 2; bb++) {
            unsigned int alo[4], ahi[4];
            #pragma unroll
            for (int d = 0; d < 4; d++) {
                alo[d] = pack_bf2(accA[bb][d][0], accA[bb][d][1]);
                ahi[d] = pack_bf2(accB[bb][d][0], accB[bb][d][1]);
            }
            memcpy(&a0[bb], alo, 16);
            memcpy(&a1[bb], ahi, 16);
        }
        #pragma unroll
        for (int j = 0; j < 4; j++) {
            frag16 blo = *(const frag16*)(wrow + (size_t)(j * 16 + m) * KP + (2 * k) * 32);
            frag16 bhi = *(const frag16*)(wrow + (size_t)(j * 16 + m) * KP + (2 * k + 1) * 32);
            c[0][j] = __builtin_amdgcn_mfma_f32_16x16x32_bf16(a0[0], blo, c[0][j], 0, 0, 0);
            c[0][j] = __builtin_amdgcn_mfma_f32_16x16x32_bf16(a1[0], bhi, c[0][j], 0, 0, 0);
            c[1][j] = __builtin_amdgcn_mfma_f32_16x16x32_bf16(a0[1], blo, c[1][j], 0, 0, 0);
            c[1][j] = __builtin_amdgcn_mfma_f32_16x16x32_bf16(a1[1], bhi, c[1][j], 0, 0, 0);
        }
    }

    // epilogue: D[row = q*4+i (vertex)][col = m+16j (out)], + bias, float2 stores
    int nbase = n0 + q * 4;
    #pragma unroll
    for (int bb = 0; bb < 2; bb++) {
        size_t outb = (size_t)(2 * bp + bb) * NO * NV;
        #pragma unroll
        for (int j = 0; j < 4; j++) {
            int o = j * 16 + m;
            float bo = bias[o];
            f32x4 vv = c[bb][j];
            float* op = out + outb + (size_t)o * NV + nbase;
            if (nbase + 4 <= NV) {
                *(float2*)op       = make_float2(vv[0] + bo, vv[1] + bo);
                *(float2*)(op + 2) = make_float2(vv[2] + bo, vv[3] + bo);
            } else {
                #pragma unroll
                for (int i = 0; i < 4; i++)
                    if (nbase + i < NV) op[i] = vv[i] + bo;
            }
        }
    }
}

extern "C" void kernel_launch(void* const* d_in, const int* in_sizes, int n_in,
                              void* d_out, int out_size, void* d_ws, size_t ws_size,
                              hipStream_t stream) {
    const float* x    = (const float*)d_in[0];  // (4,64,40962) fp32
    const int*   nidx = (const int*)d_in[1];    // (40962,27) int32
    const float* nwt  = (const float*)d_in[2];  // (40962,27) fp32
    const float* W    = (const float*)d_in[3];  // (64,576) fp32
    const float* bias = (const float*)d_in[4];  // (64,) fp32
    float* out = (float*)d_out;                 // (4,64,40962) fp32

    unsigned short* Wp    = (unsigned short*)d_ws;                       // 72 KB
    unsigned short* xt    = (unsigned short*)((char*)d_ws + 131072);     // 21 MB
    unsigned int*   pairs = (unsigned int*)((char*)d_ws + 131072 + (size_t)NB * NV * NC * 2);  // 4.6 MB

    prep_kernel<<<dim3((NV * NPAD + 255) / 256), 256, 0, stream>>>(W, nidx, nwt, Wp, pairs);
    transpose_kernel<<<dim3((NV + 63) / 64, NB), 256, 0, stream>>>(x, xt);
    fused_kernel<<<dim3((NV + 15) / 16, NB / 2), 64, 0, stream>>>(xt, pairs, Wp, bias, out);
}